// Round 23
// baseline (45.552 us; speedup 1.0000x reference)
//
#include <hip/hip_runtime.h>

#define TT 1024
#define LL 64
#define BB 256             // batch
#define WARM 4             // warm-up steps (contraction <= 0.462/step; r20/r22: absmax 0)
#define NWAVES 4096        // main-kernel waves (1024 blocks x 4)
#define LOG2E 1.44269504088896340736f
#define LN2   0.69314718055994530942f

typedef __fp16 h2 __attribute__((ext_vector_type(2)));
typedef int    i4 __attribute__((ext_vector_type(4)));
typedef unsigned u2v __attribute__((ext_vector_type(2)));
__device__ __forceinline__ h2  i2h(int x) { union { int i; h2 h; } u; u.i = x; return u.h; }
__device__ __forceinline__ int h2i(h2 x)  { union { int i; h2 h; } u; u.h = x; return u.i; }

// HALF-WAVE STATE SPLIT (r23): r22's per-CU LDS-pipe accounting (16 waves x
// ~9 DS ops x ~12cy per step ~ measured wall; VALUBusy 37% = SIMDs starved
// by the shared LDS pipe) says DS ops/step is the bound. This round halves
// broadcast traffic: lane j (h=j>>5, k=j&31) owns state pair (2k,2k+1) and
// computes HALF of each dot over i in [32h,32h+32) -> reads only its half
// of the u-strip (4 ds_read_b128, 64B). Halves combine IN-REGISTER via
// v_permlane32_swap (VALU, not DS): {a,b}=swap(pk,pk) -> a[l]=pk[l&31],
// b[l]=pk[32|(l&31)]; a+b (v_pk_add_f16) = full dot for states (2k,2k+1),
// duplicated across half-waves = exactly the strip-write pair layout
// (lanes<32 write shb[lane]). DS/step 9 -> 5. MACs unchanged (32 fdot2).
// MEAS gains a -1 dup correction (every state counted twice). Renorm pin
// [2^-2,2^-1) gives the f16 half-sums headroom (<= ~44 e^spread; r20's
// f16-accumulate passed with less).
//
// Structure (proven r13-r22): work_b = max(slen_b-1,1), prefix -> meta,
// K = ceil(W/NWAVES); wave wid owns [wid*K,(wid+1)*K) binary-searched into
// per-seq pieces. Piece [lo,hi): warm-start max(lo-WARM,1); delta =
// A(u@hi-1)-A(u@lo-1) telescopes to log_norm (positive transfer operator,
// Hilbert diam of E=exp(trans) <= 2 -> contraction 0.462/step). lo==1
// exact; slen=1 measures logsumexp(logits[0]) at init. Warm = exactly WARM
// steps when lo>1 with in-warm wave-uniform measure hooks; main =
// guard-free x8 blocks + tail. Rows: rolling 32-bit float2 offset, wrap
// (off+32)&32767 stays in-sequence; wrapped rows never consumed.

#if __has_builtin(__builtin_amdgcn_permlane32_swap)
#define HAVE_PSWAP 1
#endif

__global__ __launch_bounds__(256) void crf_prefix_kernel(
    const int* __restrict__ seq_lens, int* __restrict__ meta)
{
    __shared__ int sbuf[BB];
    const int tid = threadIdx.x;
    int wv = 0;
    if (tid < BB) { int sl = seq_lens[tid]; wv = (sl > 1) ? (sl - 1) : 1; }
    sbuf[tid] = wv;
    __syncthreads();
    for (int off = 1; off < BB; off <<= 1) {
        int v = (tid >= off) ? sbuf[tid - off] : 0;
        __syncthreads();
        sbuf[tid] += v;
        __syncthreads();
    }
    meta[tid + 1] = sbuf[tid];
    if (tid == 0) {
        meta[0] = 0;
        int W = sbuf[BB - 1];
        meta[BB + 1] = (W + NWAVES - 1) / NWAVES;   // K
    }
}

__global__ __launch_bounds__(256) void crf_piece_kernel(
    const float* __restrict__ logits,    // [B][T][L]
    const int*   __restrict__ labels,    // [B][T]
    const int*   __restrict__ seq_lens,  // [B]
    const float* __restrict__ trans,     // [L][L]
    const int*   __restrict__ meta,      // [258] prefix + K
    float*       __restrict__ part)      // [NWAVES]
{
    __shared__ __align__(16) int shq[4][32];   // per-wave pair-word strip
    const int wid  = blockIdx.x * 4 + (threadIdx.x >> 6);
    const int lane = threadIdx.x & 63;
    const int h    = lane >> 5;          // half index
    const int k    = lane & 31;          // state-pair index: states 2k, 2k+1
    int* const shb = &shq[threadIdx.x >> 6][0];
    const int hb   = 16 * h;             // this lane's strip half (words)

    // one-time per wave: E-pairs along i (own half) for columns 2k, 2k+1
    int ejX[16], ejY[16];
    #pragma unroll
    for (int m = 0; m < 16; ++m) {
        const int i0 = 32 * h + 2 * m;
        float e00 = __builtin_amdgcn_exp2f(trans[i0 * LL + 2 * k] * LOG2E);
        float e10 = __builtin_amdgcn_exp2f(trans[(i0 + 1) * LL + 2 * k] * LOG2E);
        float e01 = __builtin_amdgcn_exp2f(trans[i0 * LL + 2 * k + 1] * LOG2E);
        float e11 = __builtin_amdgcn_exp2f(trans[(i0 + 1) * LL + 2 * k + 1] * LOG2E);
        ejX[m] = h2i(__builtin_amdgcn_cvt_pkrtz(e00, e10));
        ejY[m] = h2i(__builtin_amdgcn_cvt_pkrtz(e01, e11));
    }

    const int W = meta[BB];
    const int K = meta[BB + 1];
    int g0 = wid * K;
    int g1 = g0 + K; g1 = (g1 < W) ? g1 : W;

// renorm pin [2^-2, 2^-1): headroom for f16 half-sums
#define RENORM2(V0, V1) { \
    int eb_ = (__builtin_amdgcn_readfirstlane(__float_as_int(V0)) >> 23) & 0xFF; \
    C += eb_ - 125; \
    float scl_ = __int_as_float((252 - eb_) << 23); \
    u0 = (V0) * scl_; u1 = (V1) * scl_; \
}
// publish: lanes<32 store pair word (u_2k, u_2k+1) to shb[k]; order-pin fence
#define PUBL() { \
    int upk_ = h2i(__builtin_amdgcn_cvt_pkrtz(u0, u1)); \
    if (lane < 32) shb[lane] = upk_; \
    asm volatile("" ::: "memory"); \
}
// measure: states duplicated across half-waves -> subtract 1 in log2
#define MEAS(OUT) { \
    float us_ = u0 + u1; \
    _Pragma("unroll") \
    for (int off_ = 32; off_; off_ >>= 1) us_ += __shfl_xor(us_, off_, 64); \
    OUT = ((float)C + __builtin_amdgcn_logf(us_) - 1.0f) * LN2; \
}
// guard-free step on ring slot I: half-strip gather + 32 fdot2 + VALU combine
#define RS(I) { \
    float ga_ = __builtin_amdgcn_exp2f(fR##I.x * LOG2E); \
    float gb_ = __builtin_amdgcn_exp2f(fR##I.y * LOG2E); \
    fR##I = lg2[ldoff]; \
    ldoff = (ldoff + 32) & (TT * 32 - 1); \
    i4 w_[4]; \
    _Pragma("unroll") \
    for (int r_ = 0; r_ < 4; ++r_) \
        __builtin_memcpy(&w_[r_], shb + hb + 4 * r_, 16); \
    float x0_ = 0.f, x1_ = 0.f, x2_ = 0.f, x3_ = 0.f; \
    float y0_ = 0.f, y1_ = 0.f, y2_ = 0.f, y3_ = 0.f; \
    _Pragma("unroll") \
    for (int r_ = 0; r_ < 4; ++r_) { \
        x0_ = __builtin_amdgcn_fdot2(i2h(w_[r_][0]), i2h(ejX[4 * r_]),     x0_, false); \
        x1_ = __builtin_amdgcn_fdot2(i2h(w_[r_][1]), i2h(ejX[4 * r_ + 1]), x1_, false); \
        x2_ = __builtin_amdgcn_fdot2(i2h(w_[r_][2]), i2h(ejX[4 * r_ + 2]), x2_, false); \
        x3_ = __builtin_amdgcn_fdot2(i2h(w_[r_][3]), i2h(ejX[4 * r_ + 3]), x3_, false); \
        y0_ = __builtin_amdgcn_fdot2(i2h(w_[r_][0]), i2h(ejY[4 * r_]),     y0_, false); \
        y1_ = __builtin_amdgcn_fdot2(i2h(w_[r_][1]), i2h(ejY[4 * r_ + 1]), y1_, false); \
        y2_ = __builtin_amdgcn_fdot2(i2h(w_[r_][2]), i2h(ejY[4 * r_ + 2]), y2_, false); \
        y3_ = __builtin_amdgcn_fdot2(i2h(w_[r_][3]), i2h(ejY[4 * r_ + 3]), y3_, false); \
    } \
    float X_ = (x0_ + x1_) + (x2_ + x3_); \
    float Y_ = (y0_ + y1_) + (y2_ + y3_); \
    int pk_ = h2i(__builtin_amdgcn_cvt_pkrtz(X_, Y_)); \
    h2 sp_; \
    { COMBINE(pk_, sp_); } \
    float v0_ = (float)sp_[0] * ga_; \
    float v1_ = (float)sp_[1] * gb_; \
    RENORM2(v0_, v1_); \
    PUBL(); \
}
#ifdef HAVE_PSWAP
#define COMBINE(PK, SP) { \
    u2v sw_ = __builtin_amdgcn_permlane32_swap((unsigned)(PK), (unsigned)(PK), false, false); \
    SP = i2h((int)sw_[0]) + i2h((int)sw_[1]); \
}
#else
#define COMBINE(PK, SP) { \
    int q_ = __shfl_xor((PK), 32, 64); \
    SP = i2h(PK) + i2h(q_); \
}
#endif
// warm step i (t = start + i): RS + wave-uniform measure hooks
#define WS(I, SLOT) { \
    RS(SLOT); \
    if (start + (I) == lo - 1) MEAS(A_in); \
    if (start + (I) == hi - 1) MEAS(A_out); \
}

    float result = 0.f;
    while (g0 < g1) {
        // binary search: largest b with meta[b] <= g0
        int blo = 0, bhi = BB;
        while (bhi - blo > 1) {
            int mid = (blo + bhi) >> 1;
            if (meta[mid] <= g0) blo = mid; else bhi = mid;
        }
        const int b  = blo;
        const int pe = meta[b + 1];
        const int units = ((g1 < pe) ? g1 : pe) - g0;
        const int lo = g0 - meta[b] + 1;
        const int slen = seq_lens[b];
        const int hi = (lo + units < slen) ? (lo + units) : slen;
        const float*  lg  = logits + (size_t)b * TT * LL;
        const float2* lg2 = (const float2*)lg;
        const int*    lab = labels + b * TT;

        // ---- path-score portion for this piece's t-range ----
        float sc = 0.f;
        for (int t0 = lo + lane; t0 < hi; t0 += 64) {
            int l1 = lab[t0];
            sc += lg[(size_t)t0 * LL + l1] + trans[lab[t0 - 1] * LL + l1];
        }
        if (lo == 1 && lane == 0) sc += lg[lab[0]];   // t = 0 unary
        #pragma unroll
        for (int off = 32; off; off >>= 1) sc += __shfl_xor(sc, off, 64);

        const int start = (lo - WARM > 1) ? (lo - WARM) : 1;   // clamped
        const int warmN = (lo > 1) ? WARM : 0;
        int C = 0;
        float u0, u1;

        // init from row start-1 (exact when start==1): u = exp(logits)
        {
            float2 r0 = lg2[k + (start - 1) * 32];
            float v0 = __builtin_amdgcn_exp2f(r0.x * LOG2E);
            float v1 = __builtin_amdgcn_exp2f(r0.y * LOG2E);
            RENORM2(v0, v1);
        }
        PUBL();

        // ring preload rows start..start+3 (in-bounds: start+3 <= 1017)
        unsigned ldoff = (unsigned)(k + start * 32);
        float2 fR0 = lg2[ldoff]; ldoff += 32;
        float2 fR1 = lg2[ldoff]; ldoff += 32;
        float2 fR2 = lg2[ldoff]; ldoff += 32;
        float2 fR3 = lg2[ldoff]; ldoff += 32;   // next load = row start+4

        float A_in = 0.f, A_out = 0.f;

        // ---- warm phase: exactly WARM steps when lo>1 (slot-aligned) ----
        if (warmN) {
            WS(0, 0); WS(1, 1); WS(2, 2); WS(3, 3);
        }

        // ---- main phase: n guard-free steps; A_out after, iff n>0 ----
        const int n = hi - start - warmN;
        if (n > 0) {
            for (int r = n >> 3; r > 0; --r) {
                RS(0); RS(1); RS(2); RS(3);
                RS(0); RS(1); RS(2); RS(3);
            }
            const int rem = n & 7;
            if (rem > 0) { RS(0);
            if (rem > 1) { RS(1);
            if (rem > 2) { RS(2);
            if (rem > 3) { RS(3);
            if (rem > 4) { RS(0);
            if (rem > 5) { RS(1);
            if (rem > 6) { RS(2); }}}}}}}
            MEAS(A_out);
        } else if (warmN == 0) {
            MEAS(A_out);   // 0-step piece (slen == 1): logsumexp(logits[0])
        }
        // else: A_out already captured in-warm (short piece)

        result += (A_out - A_in) - sc;
        g0 += units;
    }

    if (lane == 0) part[wid] = result;
}

__global__ __launch_bounds__(1024) void reduce_kernel(
    const float* __restrict__ part, float* __restrict__ out)
{
    int tid = threadIdx.x;
    float v = 0.f;
    #pragma unroll
    for (int i = 0; i < 4; ++i) v += part[tid + 1024 * i];
    #pragma unroll
    for (int off = 32; off; off >>= 1) v += __shfl_xor(v, off, 64);
    __shared__ float r[16];
    if ((tid & 63) == 0) r[tid >> 6] = v;
    __syncthreads();
    if (tid == 0) {
        float s = 0.f;
        #pragma unroll
        for (int i = 0; i < 16; ++i) s += r[i];
        out[0] = s;
    }
}

extern "C" void kernel_launch(void* const* d_in, const int* in_sizes, int n_in,
                              void* d_out, int out_size, void* d_ws, size_t ws_size,
                              hipStream_t stream) {
    const float* logits   = (const float*)d_in[0];
    const int*   labels   = (const int*)d_in[1];
    const int*   seq_lens = (const int*)d_in[2];
    const float* trans    = (const float*)d_in[3];

    int*   meta = (int*)d_ws;                         // 258 ints (<4 KB)
    float* part = (float*)((char*)d_ws + 4096);       // NWAVES floats

    crf_prefix_kernel<<<1, 256, 0, stream>>>(seq_lens, meta);
    crf_piece_kernel<<<1024, 256, 0, stream>>>(logits, labels, seq_lens, trans,
                                               meta, part);
    reduce_kernel<<<1, 1024, 0, stream>>>(part, (float*)d_out);
}